// Round 16
// baseline (78.751 us; speedup 1.0000x reference)
//
#include <hip/hip_runtime.h>
#include <hip/hip_bf16.h>

#define NPER 24
#define B_ 32
#define N_ 1024
#define F_ 128
#define H_ 64
#define E_ 16

typedef __attribute__((ext_vector_type(8))) short short8;
typedef __attribute__((ext_vector_type(4))) float f32x4;

#define GLD16(g, l) __builtin_amdgcn_global_load_lds( \
    (const __attribute__((address_space(1))) void*)(g), \
    (__attribute__((address_space(3))) void*)(l), 16, 0, 0)

static __device__ __forceinline__ unsigned short f2bf(float x) {
    union { float f; unsigned u; } v; v.f = x;
    unsigned r = v.u + 0x7fffu + ((v.u >> 16) & 1u);   // RNE
    return (unsigned short)(r >> 16);
}
static __device__ __forceinline__ float bf2f(unsigned short h) {
    union { unsigned u; float f; } v; v.u = ((unsigned)h) << 16; return v.f;
}
static __device__ __forceinline__ unsigned short f2bf_hw(float x) {
    __hip_bfloat16 h = __float2bfloat16(x);
    return *(unsigned short*)&h;
}

// ---------------------------------------------------------------------------
// P1: all prep in one launch (r15-verified).
// ---------------------------------------------------------------------------
__global__ __launch_bounds__(256) void prep_all(
    const float* __restrict__ src_emb, const float* __restrict__ tgt_emb,
    const float* __restrict__ env_features, const float* __restrict__ env_W,
    const float* __restrict__ env_b,
    const float* __restrict__ adj, const float* __restrict__ W,
    const float* __restrict__ rW,
    unsigned short* __restrict__ src_bf, unsigned short* __restrict__ tgt_bf,
    unsigned short* __restrict__ adj_bf, unsigned short* __restrict__ Wt,
    unsigned short* __restrict__ rWt)
{
    const int bid = blockIdx.x;
    if (bid < 1536) {
        const int g   = bid >> 8;                          // p-group 0..5
        const int idx = (bid & 255) * 256 + threadIdx.x;   // 0..65535
        const int n = idx >> 6, h = idx & 63;
        float e = env_b[h];
#pragma unroll
        for (int k = 0; k < E_; ++k)
            e = fmaf(env_features[n * E_ + k], env_W[k * H_ + h], e);
        e = fmaxf(e, 0.f);
#pragma unroll
        for (int pp = 0; pp < 4; ++pp) {
            const size_t off = (size_t)(g * 4 + pp) * (N_ * H_) + idx;
            src_bf[off] = f2bf(src_emb[off] + e);
            tgt_bf[off] = f2bf(tgt_emb[off] + e);
        }
    } else if (bid < 2560) {
        const size_t i = ((size_t)(bid - 1536) * 256 + threadIdx.x) * 4;
        float4 v = *(const float4*)(adj + i);
        ushort4 o;
        o.x = f2bf(v.x); o.y = f2bf(v.y); o.z = f2bf(v.z); o.w = f2bf(v.w);
        *(ushort4*)(adj_bf + i) = o;
    } else {
        const int idx = (bid - 2560) * 256 + threadIdx.x;   // 0..32767
        const int which = idx >> 14, j = idx & 16383;
        const int f = j >> 7, d = j & 127;
        if (which == 0) Wt[f * 128 + d]  = f2bf(W[d * 128 + f]);
        else            rWt[f * 128 + d] = f2bf(rW[d * 128 + f]);
    }
}

// ---------------------------------------------------------------------------
// K5: support^T (swapped GEMM) + residual, both bf16 out, MFMA. [unchanged]
// ---------------------------------------------------------------------------
__global__ __launch_bounds__(256) void gemm2_mfma(
    const float* __restrict__ x,               // [B*N][128] fp32
    const unsigned short* __restrict__ Wt,     // [128f][128d]
    const unsigned short* __restrict__ rWt,    // [128f][128d]
    const float* __restrict__ rb,              // [128]
    unsigned short* __restrict__ supT,         // [B][128f][1024m]
    unsigned short* __restrict__ resid)        // [B*N][128]
{
    const int t = threadIdx.x, w = t >> 6, l = t & 63;
    const int ln = l & 15, kb = l >> 4;
    const int mblk = w >> 1, fhalf = w & 1;
    const int row0 = blockIdx.x * 32;
    const int b   = row0 >> 10;
    const int mg0 = row0 & 1023;

    const float* xrow = x + (size_t)(row0 + mblk * 16 + ln) * 128;
    short8 xa[4];
#pragma unroll
    for (int k = 0; k < 4; ++k) {
        float4 v0 = *(const float4*)(xrow + k * 32 + kb * 8);
        float4 v1 = *(const float4*)(xrow + k * 32 + kb * 8 + 4);
        short8 s;
        s[0] = (short)f2bf(v0.x); s[1] = (short)f2bf(v0.y);
        s[2] = (short)f2bf(v0.z); s[3] = (short)f2bf(v0.w);
        s[4] = (short)f2bf(v1.x); s[5] = (short)f2bf(v1.y);
        s[6] = (short)f2bf(v1.z); s[7] = (short)f2bf(v1.w);
        xa[k] = s;
    }

    f32x4 accS[4], accR[4];
#pragma unroll
    for (int i = 0; i < 4; ++i) { accS[i] = (f32x4){0,0,0,0}; accR[i] = (f32x4){0,0,0,0}; }

#pragma unroll
    for (int k = 0; k < 4; ++k) {
#pragma unroll
        for (int fb = 0; fb < 4; ++fb) {
            int fr = (fhalf * 4 + fb) * 16 + ln;
            short8 wa = *(const short8*)(Wt  + (size_t)fr * 128 + k * 32 + kb * 8);
            short8 wb = *(const short8*)(rWt + (size_t)fr * 128 + k * 32 + kb * 8);
            accS[fb] = __builtin_amdgcn_mfma_f32_16x16x32_bf16(wa, xa[k], accS[fb], 0, 0, 0);
            accR[fb] = __builtin_amdgcn_mfma_f32_16x16x32_bf16(xa[k], wb, accR[fb], 0, 0, 0);
        }
    }

#pragma unroll
    for (int fb = 0; fb < 4; ++fb) {
        int m = mg0 + mblk * 16 + ln;
#pragma unroll
        for (int i = 0; i < 4; ++i) {
            int f = (fhalf * 4 + fb) * 16 + kb * 4 + i;
            supT[((size_t)b * 128 + f) * 1024 + m] = f2bf(accS[fb][i]);
        }
    }
#pragma unroll
    for (int fb = 0; fb < 4; ++fb) {
        int f = (fhalf * 4 + fb) * 16 + ln;
        float rbf = rb[f];
#pragma unroll
        for (int i = 0; i < 4; ++i) {
            size_t row = (size_t)row0 + mblk * 16 + kb * 4 + i;
            resid[row * 128 + f] = f2bf(fmaxf(accR[fb][i] + rbf, 0.f));
        }
    }
}

// ---------------------------------------------------------------------------
// K6a: score_mfma — materialize S[p][n][m] = bf16(relu(src·tgt^T)*adj) for
// all 24 periods. One-shot per block (no chunk loop): block = (p, 64n, 64m),
// grid 6144, 256 thr / 4 waves. Stage src+tgt tiles (16KB) via GLD16
// (swizzle c^(r&7) both sides); wave w owns 16-n strip: 8 MFMA, mask,
// scattered uint2 writes (8B contiguous per lane). Massive TLP hides all
// latency — no serial drain chain anywhere.
// ---------------------------------------------------------------------------
__global__ __launch_bounds__(256, 2) void score_mfma(
    const unsigned short* __restrict__ src_bf,  // [P][N][64]
    const unsigned short* __restrict__ tgt_bf,  // [P][N][64]
    const unsigned short* __restrict__ adj_bf,  // [N][N]
    unsigned short* __restrict__ S)             // [P][N][N]
{
    __shared__ unsigned short s_src[64 * 64] __attribute__((aligned(16)));  // 8KB
    __shared__ unsigned short s_tgt[64 * 64] __attribute__((aligned(16)));  // 8KB

    const int bid = blockIdx.x;              // 0..6143
    const int p   = bid >> 8;                // 0..23
    const int rem = bid & 255;
    const int n0  = (rem >> 4) * 64;
    const int m0  = (rem & 15) * 64;

    const int t = threadIdx.x, w = t >> 6, l = t & 63;
    const int ln = l & 15, kb = l >> 4;

    const unsigned short* srcg = src_bf + (size_t)p * N_ * H_;
    const unsigned short* tgtg = tgt_bf + (size_t)p * N_ * H_;

    // stage both tiles, swizzled source (c^(r&7)), linear LDS dest
#pragma unroll
    for (int j = 0; j < 2; ++j) {
        const int te = j * 256 + t;
        const int r = te >> 3, c = te & 7;
        GLD16(srcg + (size_t)(n0 + r) * H_ + (c ^ (r & 7)) * 8, &s_src[te * 8]);
        GLD16(tgtg + (size_t)(m0 + r) * H_ + (c ^ (r & 7)) * 8, &s_tgt[te * 8]);
    }
    asm volatile("s_waitcnt vmcnt(0) lgkmcnt(0)" ::: "memory");
    __builtin_amdgcn_s_barrier();

    // wave w: n-strip rows n0 + w*16 + ln
    const int rs = w * 16 + ln;
    short8 sfrag[2];
    sfrag[0] = *(const short8*)(&s_src[rs * 64 + ((kb) ^ (rs & 7)) * 8]);
    sfrag[1] = *(const short8*)(&s_src[rs * 64 + ((4 + kb) ^ (rs & 7)) * 8]);

    const unsigned short* adjp = adj_bf + (size_t)(n0 + w * 16 + ln) * N_ + m0;
    unsigned short* Sp = S + ((size_t)p * N_ + n0 + w * 16 + ln) * N_ + m0;

#pragma unroll
    for (int mt = 0; mt < 4; ++mt) {
        const int trow = mt * 16 + ln;
        short8 tf0 = *(const short8*)(&s_tgt[trow * 64 + ((kb) ^ (trow & 7)) * 8]);
        short8 tf1 = *(const short8*)(&s_tgt[trow * 64 + ((4 + kb) ^ (trow & 7)) * 8]);
        f32x4 c = (f32x4){0, 0, 0, 0};
        c = __builtin_amdgcn_mfma_f32_16x16x32_bf16(tf0, sfrag[0], c, 0, 0, 0);
        c = __builtin_amdgcn_mfma_f32_16x16x32_bf16(tf1, sfrag[1], c, 0, 0, 0);
        // lane: score[m = mt*16+kb*4+i][n = ln]  (r9-verified layout)
        const ushort4 a = *(const ushort4*)(adjp + mt * 16 + kb * 4);
        uint2 q;
        q.x = (unsigned)f2bf_hw(fmaxf(c[0], 0.f) * bf2f(a.x))
            | ((unsigned)f2bf_hw(fmaxf(c[1], 0.f) * bf2f(a.y)) << 16);
        q.y = (unsigned)f2bf_hw(fmaxf(c[2], 0.f) * bf2f(a.z))
            | ((unsigned)f2bf_hw(fmaxf(c[3], 0.f) * bf2f(a.w)) << 16);
        // S[n][m]: lane's n-row, 4 consecutive m -> 8B contiguous
        *(uint2*)(Sp + mt * 16 + kb * 4) = q;
    }
}

// ---------------------------------------------------------------------------
// K6b: conv_mfma — PURE GEMM: out[b] = S[p(b)] @ supT[b]^T + resid.
// r10's verified shell minus the score phase. Block = (b, 64n), grid 512
// XCD-swizzled, 4 waves (wave cf owns 32 f-cols), 48KB LDS -> 3 blocks/CU.
// Per 64-m chunk: stage S-tile(8KB)+sup(16KB) via GLD16 (both-sides swizzle
// c^(r&7)); 16 MFMA/wave; ONE bar_vm0/chunk. Zero VALU produce chain.
// ---------------------------------------------------------------------------
__global__ __launch_bounds__(256, 3) void conv_mfma(
    const unsigned short* __restrict__ S,       // [P][N][N]
    const unsigned short* __restrict__ supT,    // [B][128][1024]
    const unsigned short* __restrict__ resid,   // [B*N][128]
    const float* __restrict__ bias,             // [128]
    const int* __restrict__ cyc,                // [B]
    float* __restrict__ out)                    // [B][N][128]
{
    __shared__ unsigned short s_S[2][64 * 64] __attribute__((aligned(16)));    // 2x8KB
    __shared__ unsigned short s_sup[2][128 * 64] __attribute__((aligned(16))); // 2x16KB

    const int i = blockIdx.x;                    // 0..511
    const int work = (i & 7) * 64 + (i >> 3);    // XCD k: 2 consecutive b's
    const int b  = work >> 4;
    const int n0 = (work & 15) * 64;

    const int t = threadIdx.x, w = t >> 6, l = t & 63;
    const int ln = l & 15, kb = l >> 4;
    const int p = ((cyc[b] % NPER) + NPER) % NPER;
    const int cf = w;                            // 32 f-cols per wave

    const unsigned short* Sg   = S + ((size_t)p * N_ + n0) * N_;
    const unsigned short* supg = supT + (size_t)b * F_ * N_;

    f32x4 acc[4][2];
#pragma unroll
    for (int q = 0; q < 4; ++q)
#pragma unroll
        for (int fb = 0; fb < 2; ++fb) acc[q][fb] = (f32x4){0, 0, 0, 0};

    auto stage = [&](int buf, int m0) {
        // S tile: 64 n-rows x 8 chunks(16B) of the 64-m slice
#pragma unroll
        for (int j = 0; j < 2; ++j) {
            const int te = j * 256 + t;
            const int r = te >> 3, c = te & 7;
            GLD16(Sg + (size_t)r * N_ + m0 + (c ^ (r & 7)) * 8, &s_S[buf][te * 8]);
        }
        // sup tile: 128 f-rows x 8 chunks(16B)
#pragma unroll
        for (int j = 0; j < 4; ++j) {
            const int te = j * 256 + t;
            const int r = te >> 3, c = te & 7;
            GLD16(supg + (size_t)r * N_ + m0 + (c ^ (r & 7)) * 8, &s_sup[buf][te * 8]);
        }
    };

    auto conv = [&](int buf) {
#pragma unroll
        for (int ks = 0; ks < 2; ++ks) {
            short8 bfrag[2];
#pragma unroll
            for (int fb = 0; fb < 2; ++fb) {
                const int frow = cf * 32 + fb * 16 + ln;
                bfrag[fb] = *(const short8*)(
                    &s_sup[buf][frow * 64 + ((ks * 4 + kb) ^ (frow & 7)) * 8]);
            }
#pragma unroll
            for (int nt2 = 0; nt2 < 4; ++nt2) {
                const int rn = nt2 * 16 + ln;
                short8 af = *(const short8*)(
                    &s_S[buf][rn * 64 + ((ks * 4 + kb) ^ (rn & 7)) * 8]);
#pragma unroll
                for (int fb = 0; fb < 2; ++fb)
                    acc[nt2][fb] = __builtin_amdgcn_mfma_f32_16x16x32_bf16(
                        af, bfrag[fb], acc[nt2][fb], 0, 0, 0);
            }
        }
    };

    auto bar_vm0 = []() {
        asm volatile("s_waitcnt vmcnt(0) lgkmcnt(0)" ::: "memory");
        __builtin_amdgcn_s_barrier();
    };

    stage(0, 0);
    bar_vm0();

    for (int tt = 0; tt < 16; tt += 2) {
        stage(1, (tt + 1) * 64);
        conv(0);
        bar_vm0();

        if (tt + 2 < 16) stage(0, (tt + 2) * 64);
        conv(1);
        bar_vm0();
    }

    // epilogue: out = relu(conv + bias + residual)
#pragma unroll
    for (int nt2 = 0; nt2 < 4; ++nt2)
#pragma unroll
    for (int fb = 0; fb < 2; ++fb) {
        const int f = cf * 32 + fb * 16 + ln;
        const float bi = bias[f];
#pragma unroll
        for (int ii = 0; ii < 4; ++ii) {
            const int n = n0 + nt2 * 16 + kb * 4 + ii;
            const size_t o = ((size_t)b * N_ + n) * F_ + f;
            out[o] = fmaxf(acc[nt2][fb][ii] + bi + bf2f(resid[o]), 0.f);
        }
    }
}

// ---------------------------------------------------------------------------
extern "C" void kernel_launch(void* const* d_in, const int* in_sizes, int n_in,
                              void* d_out, int out_size, void* d_ws, size_t ws_size,
                              hipStream_t stream) {
    const float* input_features = (const float*)d_in[0];
    const int*   cycle_indices  = (const int*)  d_in[1];
    const float* weight         = (const float*)d_in[2];
    const float* bias           = (const float*)d_in[3];
    const float* src_emb        = (const float*)d_in[4];
    const float* tgt_emb        = (const float*)d_in[5];
    const float* env_W          = (const float*)d_in[6];
    const float* env_b          = (const float*)d_in[7];
    const float* res_W          = (const float*)d_in[8];
    const float* res_b          = (const float*)d_in[9];
    const float* static_adj     = (const float*)d_in[10];
    const float* env_features   = (const float*)d_in[11];
    float* out = (float*)d_out;

    // workspace layout (~75.6 MiB; ws proven ~252 MB via fillBuffer WRITE_SIZE)
    char* wsb = (char*)d_ws;
    unsigned short* src_bf = (unsigned short*)wsb;               // 3145728 B
    unsigned short* tgt_bf = src_bf + (size_t)NPER * N_ * H_;    // 3145728 B
    unsigned short* Wt     = tgt_bf + (size_t)NPER * N_ * H_;    // 32768 B
    unsigned short* rWt    = Wt + 16384;                         // 32768 B
    unsigned short* supT   = rWt + 16384;                        // 8388608 B
    unsigned short* resid  = supT + (size_t)B_ * F_ * N_;        // 8388608 B
    unsigned short* adj_bf = resid + (size_t)B_ * N_ * F_;       // 2097152 B
    unsigned short* S      = adj_bf + (size_t)N_ * N_;           // 50331648 B

    prep_all<<<2688, 256, 0, stream>>>(
        src_emb, tgt_emb, env_features, env_W, env_b,
        static_adj, weight, res_W,
        src_bf, tgt_bf, adj_bf, Wt, rWt);

    score_mfma<<<NPER * 256, 256, 0, stream>>>(src_bf, tgt_bf, adj_bf, S);

    gemm2_mfma<<<(B_ * N_) / 32, 256, 0, stream>>>(
        input_features, Wt, rWt, res_b, supT, resid);

    conv_mfma<<<512, 256, 0, stream>>>(
        S, supT, resid, bias, cycle_indices, out);
}

// Round 17
// 54.268 us; speedup vs baseline: 1.4511x; 1.4511x over previous
//
#include <hip/hip_runtime.h>
#include <hip/hip_bf16.h>

#define NPER 24
#define B_ 32
#define N_ 1024
#define F_ 128
#define H_ 64
#define E_ 16

typedef __attribute__((ext_vector_type(8))) short short8;
typedef __attribute__((ext_vector_type(4))) float f32x4;

#define GLD16(g, l) __builtin_amdgcn_global_load_lds( \
    (const __attribute__((address_space(1))) void*)(g), \
    (__attribute__((address_space(3))) void*)(l), 16, 0, 0)

static __device__ __forceinline__ unsigned short f2bf(float x) {
    union { float f; unsigned u; } v; v.f = x;
    unsigned r = v.u + 0x7fffu + ((v.u >> 16) & 1u);   // RNE
    return (unsigned short)(r >> 16);
}
static __device__ __forceinline__ float bf2f(unsigned short h) {
    union { unsigned u; float f; } v; v.u = ((unsigned)h) << 16; return v.f;
}
static __device__ __forceinline__ unsigned short f2bf_hw(float x) {
    __hip_bfloat16 h = __float2bfloat16(x);
    return *(unsigned short*)&h;
}

// ---------------------------------------------------------------------------
// P1: all prep in one launch.
//   [0,1536):     src/tgt bf16 (6 p-groups x 4 periods)
//   [1536,2560):  adj -> bf16
//   [2560,2688):  W / res_W transpose -> bf16
//   [2688,6784):  x -> bf16 (vectorized)
// ---------------------------------------------------------------------------
__global__ __launch_bounds__(256) void prep_all(
    const float* __restrict__ src_emb, const float* __restrict__ tgt_emb,
    const float* __restrict__ env_features, const float* __restrict__ env_W,
    const float* __restrict__ env_b,
    const float* __restrict__ adj, const float* __restrict__ W,
    const float* __restrict__ rW, const float* __restrict__ x,
    unsigned short* __restrict__ src_bf, unsigned short* __restrict__ tgt_bf,
    unsigned short* __restrict__ adj_bf, unsigned short* __restrict__ Wt,
    unsigned short* __restrict__ rWt, unsigned short* __restrict__ x_bf)
{
    const int bid = blockIdx.x;
    if (bid < 1536) {
        const int g   = bid >> 8;                          // p-group 0..5
        const int idx = (bid & 255) * 256 + threadIdx.x;   // 0..65535
        const int n = idx >> 6, h = idx & 63;
        float e = env_b[h];
#pragma unroll
        for (int k = 0; k < E_; ++k)
            e = fmaf(env_features[n * E_ + k], env_W[k * H_ + h], e);
        e = fmaxf(e, 0.f);
#pragma unroll
        for (int pp = 0; pp < 4; ++pp) {
            const size_t off = (size_t)(g * 4 + pp) * (N_ * H_) + idx;
            src_bf[off] = f2bf(src_emb[off] + e);
            tgt_bf[off] = f2bf(tgt_emb[off] + e);
        }
    } else if (bid < 2560) {
        const size_t i = ((size_t)(bid - 1536) * 256 + threadIdx.x) * 4;
        float4 v = *(const float4*)(adj + i);
        ushort4 o;
        o.x = f2bf(v.x); o.y = f2bf(v.y); o.z = f2bf(v.z); o.w = f2bf(v.w);
        *(ushort4*)(adj_bf + i) = o;
    } else if (bid < 2688) {
        const int idx = (bid - 2560) * 256 + threadIdx.x;   // 0..32767
        const int which = idx >> 14, j = idx & 16383;
        const int f = j >> 7, d = j & 127;
        if (which == 0) Wt[f * 128 + d]  = f2bf(W[d * 128 + f]);
        else            rWt[f * 128 + d] = f2bf(rW[d * 128 + f]);
    } else {
        const size_t i = ((size_t)(bid - 2688) * 256 + threadIdx.x) * 4;
        float4 v = *(const float4*)(x + i);
        ushort4 o;
        o.x = f2bf(v.x); o.y = f2bf(v.y); o.z = f2bf(v.z); o.w = f2bf(v.w);
        *(ushort4*)(x_bf + i) = o;
    }
}

// ---------------------------------------------------------------------------
// K5: support^T + residual — LDS-STAGED version (r9's measured medicine
// applied to gemm2: replace scattered per-lane Wt/rWt/x fragment loads with
// coalesced GLD16 staging + swizzled LDS reads). Block = 64 x-rows, grid
// 512, 4 waves; wave w owns 16-row strip, all 128 f. Accumulation/write
// formulas identical to the r2-verified gemm2 (k outer, ff inner).
// ---------------------------------------------------------------------------
__global__ __launch_bounds__(256, 2) void gemm2_mfma(
    const unsigned short* __restrict__ x_bf,   // [B*N][128]
    const unsigned short* __restrict__ Wt,     // [128f][128d]
    const unsigned short* __restrict__ rWt,    // [128f][128d]
    const float* __restrict__ rb,              // [128]
    unsigned short* __restrict__ supT,         // [B][128f][1024m]
    unsigned short* __restrict__ resid)        // [B*N][128]
{
    __shared__ unsigned short s_w[128 * 128] __attribute__((aligned(16)));  // 32KB
    __shared__ unsigned short s_r[128 * 128] __attribute__((aligned(16)));  // 32KB
    __shared__ unsigned short s_x[64 * 128]  __attribute__((aligned(16)));  // 16KB

    const int t = threadIdx.x, w = t >> 6, l = t & 63;
    const int ln = l & 15, kb = l >> 4;
    const size_t row0 = (size_t)blockIdx.x * 64;
    const int b   = (int)(row0 >> 10);
    const int mg0 = (int)(row0 & 1023);

    // stage Wt/rWt: 128 rows x 16 chunks(16B); src-side swizzle c^(r&7)
#pragma unroll
    for (int j = 0; j < 8; ++j) {
        const int te = j * 256 + t;
        const int r = te >> 4, c = te & 15;
        GLD16(Wt  + (size_t)r * 128 + (c ^ (r & 7)) * 8, &s_w[te * 8]);
        GLD16(rWt + (size_t)r * 128 + (c ^ (r & 7)) * 8, &s_r[te * 8]);
    }
    // stage x: 64 rows x 16 chunks(16B)
#pragma unroll
    for (int j = 0; j < 4; ++j) {
        const int te = j * 256 + t;
        const int r = te >> 4, c = te & 15;
        GLD16(x_bf + row0 * 128 + (size_t)r * 128 + (c ^ (r & 7)) * 8,
              &s_x[te * 8]);
    }
    asm volatile("s_waitcnt vmcnt(0) lgkmcnt(0)" ::: "memory");
    __builtin_amdgcn_s_barrier();

    f32x4 accS[8], accR[8];
#pragma unroll
    for (int q = 0; q < 8; ++q) { accS[q] = (f32x4){0,0,0,0}; accR[q] = (f32x4){0,0,0,0}; }

    const int xr = w * 16 + ln;            // wave's x row (local)
#pragma unroll
    for (int k = 0; k < 4; ++k) {
        short8 xa = *(const short8*)(&s_x[xr * 128 + ((k * 4 + kb) ^ (xr & 7)) * 8]);
#pragma unroll
        for (int ff = 0; ff < 8; ++ff) {
            const int fr = ff * 16 + ln;
            short8 wa = *(const short8*)(&s_w[fr * 128 + ((k * 4 + kb) ^ (fr & 7)) * 8]);
            short8 wb = *(const short8*)(&s_r[fr * 128 + ((k * 4 + kb) ^ (fr & 7)) * 8]);
            accS[ff] = __builtin_amdgcn_mfma_f32_16x16x32_bf16(wa, xa, accS[ff], 0, 0, 0);
            accR[ff] = __builtin_amdgcn_mfma_f32_16x16x32_bf16(xa, wb, accR[ff], 0, 0, 0);
        }
    }

    // supT: C[f][m], m = mg0 + w*16 + ln, f = ff*16 + kb*4 + i  [r2-verified]
#pragma unroll
    for (int ff = 0; ff < 8; ++ff) {
        const int m = mg0 + w * 16 + ln;
#pragma unroll
        for (int i = 0; i < 4; ++i) {
            const int f = ff * 16 + kb * 4 + i;
            supT[((size_t)b * 128 + f) * 1024 + m] = f2bf(accS[ff][i]);
        }
    }
    // resid: C[m][f], f = ff*16 + ln, row = row0 + w*16 + kb*4 + i
#pragma unroll
    for (int ff = 0; ff < 8; ++ff) {
        const int f = ff * 16 + ln;
        const float rbf = rb[f];
#pragma unroll
        for (int i = 0; i < 4; ++i) {
            const size_t row = row0 + w * 16 + kb * 4 + i;
            resid[row * 128 + f] = f2bf(fmaxf(accR[ff][i] + rbf, 0.f));
        }
    }
}

// ---------------------------------------------------------------------------
// K6: r10-EXACT fused conv (best measured: conv ~34 us, total 64.1).
// ---------------------------------------------------------------------------
__global__ __launch_bounds__(256, 2) void conv_mfma(
    const unsigned short* __restrict__ src_bf,  // [P][N][64]
    const unsigned short* __restrict__ tgt_bf,  // [P][N][64]
    const unsigned short* __restrict__ adj_bf,  // [N][N]
    const unsigned short* __restrict__ supT,    // [B][128][1024]
    const unsigned short* __restrict__ resid,   // [B*N][128]
    const float* __restrict__ bias,             // [128]
    const int* __restrict__ cyc,                // [B]
    float* __restrict__ out)                    // [B][N][128]
{
    __shared__ unsigned short s_tgt[2][64 * 64] __attribute__((aligned(16)));
    __shared__ unsigned short s_sup[2][128 * 64] __attribute__((aligned(16)));
    __shared__ unsigned short s_a[64][72] __attribute__((aligned(16)));

    const int i = blockIdx.x;                    // 0..511
    const int work = (i & 7) * 64 + (i >> 3);    // XCD k: 2 consecutive b's
    const int b  = work >> 4;
    const int n0 = (work & 15) * 64;

    const int t = threadIdx.x, w = t >> 6, l = t & 63;
    const int ln = l & 15, kb = l >> 4;
    const int p = ((cyc[b] % NPER) + NPER) % NPER;

    const int sn = w >> 1, sm = w & 1;   // score: 32n x 32m quarter per wave
    const int cf = w;                    // conv: 32 f columns per wave

    short8 sfrag[2][2];
#pragma unroll
    for (int nt = 0; nt < 2; ++nt)
#pragma unroll
        for (int k2 = 0; k2 < 2; ++k2)
            sfrag[nt][k2] = *(const short8*)(
                src_bf + ((size_t)p * N_ + n0 + sn * 32 + nt * 16 + ln) * H_ + k2 * 32 + kb * 8);

    const unsigned short* tgtg = tgt_bf + (size_t)p * N_ * H_;
    const unsigned short* supg = supT + (size_t)b * F_ * N_;

    f32x4 acc[4][2];
#pragma unroll
    for (int q = 0; q < 4; ++q)
#pragma unroll
        for (int fb = 0; fb < 2; ++fb) acc[q][fb] = (f32x4){0, 0, 0, 0};

    auto stage = [&](int buf, int m0) {
#pragma unroll
        for (int j = 0; j < 2; ++j) {
            const int te = j * 256 + t;
            const int r = te >> 3, c = te & 7;
            GLD16(tgtg + (size_t)(m0 + r) * H_ + (c ^ (r & 7)) * 8,
                  &s_tgt[buf][te * 8]);
        }
#pragma unroll
        for (int j = 0; j < 4; ++j) {
            const int te = j * 256 + t;
            const int r = te >> 3, c = te & 7;
            GLD16(supg + (size_t)r * N_ + m0 + (c ^ (r & 7)) * 8,
                  &s_sup[buf][te * 8]);
        }
    };

    auto loadAdj = [&](int m0, ushort4 (&av)[2][2]) {
#pragma unroll
        for (int nt = 0; nt < 2; ++nt)
#pragma unroll
            for (int mt = 0; mt < 2; ++mt)
                av[nt][mt] = *(const ushort4*)(
                    adj_bf + (size_t)(n0 + sn * 32 + nt * 16 + ln) * N_
                           + m0 + sm * 32 + mt * 16 + kb * 4);
    };

    auto score = [&](int buf, const ushort4 (&av)[2][2]) {
        short8 tf[2][2];
#pragma unroll
        for (int mt = 0; mt < 2; ++mt)
#pragma unroll
            for (int k2 = 0; k2 < 2; ++k2) {
                const int trow = sm * 32 + mt * 16 + ln;
                tf[mt][k2] = *(const short8*)(
                    &s_tgt[buf][trow * 64 + ((k2 * 4 + kb) ^ (trow & 7)) * 8]);
            }
#pragma unroll
        for (int nt = 0; nt < 2; ++nt)
#pragma unroll
            for (int mt = 0; mt < 2; ++mt) {
                f32x4 c = (f32x4){0, 0, 0, 0};
                c = __builtin_amdgcn_mfma_f32_16x16x32_bf16(tf[mt][0], sfrag[nt][0], c, 0, 0, 0);
                c = __builtin_amdgcn_mfma_f32_16x16x32_bf16(tf[mt][1], sfrag[nt][1], c, 0, 0, 0);
                const int nl = sn * 32 + nt * 16 + ln;
                const int ml = sm * 32 + mt * 16 + kb * 4;
                const ushort4 a = av[nt][mt];
                uint2 q;
                q.x = (unsigned)f2bf_hw(fmaxf(c[0], 0.f) * bf2f(a.x))
                    | ((unsigned)f2bf_hw(fmaxf(c[1], 0.f) * bf2f(a.y)) << 16);
                q.y = (unsigned)f2bf_hw(fmaxf(c[2], 0.f) * bf2f(a.z))
                    | ((unsigned)f2bf_hw(fmaxf(c[3], 0.f) * bf2f(a.w)) << 16);
                *(uint2*)(&s_a[nl][ml]) = q;
            }
    };

    auto conv = [&](int buf) {
#pragma unroll
        for (int ks = 0; ks < 2; ++ks) {
            short8 bfrag[2];
#pragma unroll
            for (int fb = 0; fb < 2; ++fb) {
                const int frow = cf * 32 + fb * 16 + ln;
                bfrag[fb] = *(const short8*)(
                    &s_sup[buf][frow * 64 + ((ks * 4 + kb) ^ (frow & 7)) * 8]);
            }
#pragma unroll
            for (int nt2 = 0; nt2 < 4; ++nt2) {
                short8 af = *(const short8*)(&s_a[nt2 * 16 + ln][ks * 32 + kb * 8]);
#pragma unroll
                for (int fb = 0; fb < 2; ++fb)
                    acc[nt2][fb] = __builtin_amdgcn_mfma_f32_16x16x32_bf16(
                        af, bfrag[fb], acc[nt2][fb], 0, 0, 0);
            }
        }
    };

    auto bar_lgkm = []() {
        asm volatile("s_waitcnt lgkmcnt(0)" ::: "memory");
        __builtin_amdgcn_s_barrier();
    };
    auto bar_vm0 = []() {
        asm volatile("s_waitcnt vmcnt(0) lgkmcnt(0)" ::: "memory");
        __builtin_amdgcn_s_barrier();
    };

    ushort4 avA[2][2], avB[2][2];

    stage(0, 0);
    loadAdj(0, avA);
    bar_vm0();

    for (int tt = 0; tt < 16; tt += 2) {
        stage(1, (tt + 1) * 64);
        loadAdj((tt + 1) * 64, avB);
        score(0, avA);
        bar_lgkm();
        conv(0);
        bar_vm0();

        if (tt + 2 < 16) {
            stage(0, (tt + 2) * 64);
            loadAdj((tt + 2) * 64, avA);
        }
        score(1, avB);
        bar_lgkm();
        conv(1);
        bar_vm0();
    }

#pragma unroll
    for (int nt2 = 0; nt2 < 4; ++nt2)
#pragma unroll
    for (int fb = 0; fb < 2; ++fb) {
        const int f = cf * 32 + fb * 16 + ln;
        const float bi = bias[f];
#pragma unroll
        for (int ii = 0; ii < 4; ++ii) {
            const int n = n0 + nt2 * 16 + kb * 4 + ii;
            const size_t o = ((size_t)b * N_ + n) * F_ + f;
            out[o] = fmaxf(acc[nt2][fb][ii] + bi + bf2f(resid[o]), 0.f);
        }
    }
}

// ---------------------------------------------------------------------------
extern "C" void kernel_launch(void* const* d_in, const int* in_sizes, int n_in,
                              void* d_out, int out_size, void* d_ws, size_t ws_size,
                              hipStream_t stream) {
    const float* input_features = (const float*)d_in[0];
    const int*   cycle_indices  = (const int*)  d_in[1];
    const float* weight         = (const float*)d_in[2];
    const float* bias           = (const float*)d_in[3];
    const float* src_emb        = (const float*)d_in[4];
    const float* tgt_emb        = (const float*)d_in[5];
    const float* env_W          = (const float*)d_in[6];
    const float* env_b          = (const float*)d_in[7];
    const float* res_W          = (const float*)d_in[8];
    const float* res_b          = (const float*)d_in[9];
    const float* static_adj     = (const float*)d_in[10];
    const float* env_features   = (const float*)d_in[11];
    float* out = (float*)d_out;

    // workspace layout (~33.6 MiB)
    char* wsb = (char*)d_ws;
    unsigned short* src_bf = (unsigned short*)wsb;               // 3145728 B
    unsigned short* tgt_bf = src_bf + (size_t)NPER * N_ * H_;    // 3145728 B
    unsigned short* Wt     = tgt_bf + (size_t)NPER * N_ * H_;    // 32768 B
    unsigned short* rWt    = Wt + 16384;                         // 32768 B
    unsigned short* supT   = rWt + 16384;                        // 8388608 B
    unsigned short* resid  = supT + (size_t)B_ * F_ * N_;        // 8388608 B
    unsigned short* adj_bf = resid + (size_t)B_ * N_ * F_;       // 2097152 B
    unsigned short* x_bf   = adj_bf + (size_t)N_ * N_;           // 8388608 B

    prep_all<<<6784, 256, 0, stream>>>(
        src_emb, tgt_emb, env_features, env_W, env_b,
        static_adj, weight, res_W, input_features,
        src_bf, tgt_bf, adj_bf, Wt, rWt, x_bf);

    gemm2_mfma<<<(B_ * N_) / 64, 256, 0, stream>>>(
        x_bf, Wt, rWt, res_b, supT, resid);

    conv_mfma<<<512, 256, 0, stream>>>(
        src_bf, tgt_bf, adj_bf, supT, resid, bias, cycle_indices, out);
}